// Round 1
// baseline (238.929 us; speedup 1.0000x reference)
//
#include <hip/hip_runtime.h>
#include <hip/hip_bf16.h>

#define BATCH 16384
#define F_DIM 64
#define D_DIM 32
#define H_DIM 256
#define HO_DIM 128
#define NPAIR 2016
#define CIN_DIM 2176

typedef __hip_bfloat16 bf16;
using bf16x8 = __attribute__((ext_vector_type(8))) __bf16;
using f32x4  = __attribute__((ext_vector_type(4))) float;

__device__ inline float selu_f(float v) {
    const float scale = 1.0507009873554805f;
    const float alpha = 1.6732632423543772f;
    return v > 0.f ? scale * v : scale * alpha * (__expf(v) - 1.f);
}

// out[n*K + k] = bf16(in[k*N + n]);  N must be a power of two (logN = log2(N))
__global__ void transpose_cvt(const float* __restrict__ in, bf16* __restrict__ out,
                              int K, int N, int logN) {
    int i = blockIdx.x * 256 + threadIdx.x;
    if (i >= K * N) return;
    int n = i & (N - 1), k = i >> logN;
    out[(size_t)n * K + k] = __float2bfloat16(in[i]);
}

// One wave per batch: gram = X * X^T (64x64, K=32) via 10 MFMAs (upper tiles),
// writes soi (2016 bf16) into cin[:,128:2144] and first_order into cin[:,2144:2176].
__global__ __launch_bounds__(256) void gram_first(const float* __restrict__ x,
                                                  bf16* __restrict__ cin) {
    __shared__ __align__(16) bf16 stage[4][NPAIR];
    int w = threadIdx.x >> 6, l = threadIdx.x & 63;
    int b = blockIdx.x * 4 + w;
    const float* X = x + (size_t)b * (F_DIM * D_DIM);
    int lr = l & 15, lk = l >> 4;

    bf16x8 xa[4];
    float fsum[8];
#pragma unroll
    for (int j = 0; j < 8; ++j) fsum[j] = 0.f;

#pragma unroll
    for (int ti = 0; ti < 4; ++ti) {
        const float* p = X + (ti * 16 + lr) * D_DIM + lk * 8;
        float4 f0 = *(const float4*)p;
        float4 f1 = *(const float4*)(p + 4);
        bf16x8 t;
        t[0] = (__bf16)f0.x; t[1] = (__bf16)f0.y; t[2] = (__bf16)f0.z; t[3] = (__bf16)f0.w;
        t[4] = (__bf16)f1.x; t[5] = (__bf16)f1.y; t[6] = (__bf16)f1.z; t[7] = (__bf16)f1.w;
        xa[ti] = t;
        fsum[0] += f0.x; fsum[1] += f0.y; fsum[2] += f0.z; fsum[3] += f0.w;
        fsum[4] += f1.x; fsum[5] += f1.y; fsum[6] += f1.z; fsum[7] += f1.w;
    }

    const int pi[10] = {0,0,0,0,1,1,1,2,2,3};
    const int pj[10] = {0,1,2,3,1,2,3,2,3,3};
    f32x4 zero = {0.f, 0.f, 0.f, 0.f};
#pragma unroll
    for (int p = 0; p < 10; ++p) {
        f32x4 g = __builtin_amdgcn_mfma_f32_16x16x32_bf16(xa[pi[p]], xa[pj[p]], zero, 0, 0, 0);
        int ib = pi[p] * 16 + lk * 4;
        int j  = pj[p] * 16 + lr;
#pragma unroll
        for (int r = 0; r < 4; ++r) {
            int i = ib + r;
            if (j > i) {
                int idx = (i * (127 - i)) / 2 + (j - i - 1);
                stage[w][idx] = __float2bfloat16(g[r]);
            }
        }
    }

    // first_order: reduce fsum across the 16 lanes of each lane-group
#pragma unroll
    for (int m = 1; m < 16; m <<= 1)
#pragma unroll
        for (int j = 0; j < 8; ++j)
            fsum[j] += __shfl_xor(fsum[j], m, 64);
    if (lr == 0) {
        bf16* dst = cin + (size_t)b * CIN_DIM + (HO_DIM + NPAIR) + lk * 8;
#pragma unroll
        for (int j = 0; j < 8; ++j) dst[j] = __float2bfloat16(fsum[j]);
    }

    __syncthreads();
    // coalesced copy of 4 batches x 2016 bf16 (252 uint4 per batch) to cin soi region
    const uint4* s4 = (const uint4*)&stage[0][0];
    int base_b = blockIdx.x * 4;
    for (int c = threadIdx.x; c < 4 * 252; c += 256) {
        int bb = c / 252, off = c - bb * 252;
        uint4 v = s4[c];
        *(uint4*)(cin + (size_t)(base_b + bb) * CIN_DIM + HO_DIM + off * 8) = v;
    }
}

// 4-wave (2x2) MFMA GEMM: block tile 64 x (FN*32), wave tile 32 x (FN*16).
// A: row-major [M][lda] (bf16, or fp32 converted inline when AFP32).
// BT: [N][K] bf16 (pre-transposed weights), K-contiguous.
// ACT: 0 = +bias, 1 = +bias,selu, 2 = +bias,relu then fused dot with Wc2 -> Out.
template<int K, int FN, bool AFP32, int ACT>
__global__ __launch_bounds__(256) void gemm_k(
    const void* __restrict__ Av, int lda,
    const bf16* __restrict__ BT,
    const float* __restrict__ bias,
    bf16* __restrict__ C, int ldc, int ccol,
    const float* __restrict__ Wc2, const float* __restrict__ bc2,
    float* __restrict__ Out)
{
    int tid = threadIdx.x;
    int w = tid >> 6, l = tid & 63;
    int wm = w >> 1, wn = w & 1;
    int lr = l & 15, lk = l >> 4;
    int rowbase = blockIdx.x * 64 + wm * 32;
    int colbase = wn * FN * 16;

    f32x4 acc[2][FN];
#pragma unroll
    for (int fm = 0; fm < 2; ++fm)
#pragma unroll
        for (int fn = 0; fn < FN; ++fn)
            acc[fm][fn] = (f32x4){0.f, 0.f, 0.f, 0.f};

    const float* Af = (const float*)Av;
    const bf16*  Ab = (const bf16*)Av;

    for (int k0 = 0; k0 < K; k0 += 32) {
        bf16x8 a[2], bfr[FN];
#pragma unroll
        for (int fm = 0; fm < 2; ++fm) {
            int row = rowbase + fm * 16 + lr;
            if constexpr (AFP32) {
                const float* p = Af + (size_t)row * lda + k0 + lk * 8;
                float4 f0 = *(const float4*)p;
                float4 f1 = *(const float4*)(p + 4);
                bf16x8 t;
                t[0] = (__bf16)f0.x; t[1] = (__bf16)f0.y; t[2] = (__bf16)f0.z; t[3] = (__bf16)f0.w;
                t[4] = (__bf16)f1.x; t[5] = (__bf16)f1.y; t[6] = (__bf16)f1.z; t[7] = (__bf16)f1.w;
                a[fm] = t;
            } else {
                a[fm] = *(const bf16x8*)(Ab + (size_t)row * lda + k0 + lk * 8);
            }
        }
#pragma unroll
        for (int fn = 0; fn < FN; ++fn) {
            int col = colbase + fn * 16 + lr;
            bfr[fn] = *(const bf16x8*)(BT + (size_t)col * K + k0 + lk * 8);
        }
#pragma unroll
        for (int fm = 0; fm < 2; ++fm)
#pragma unroll
            for (int fn = 0; fn < FN; ++fn)
                acc[fm][fn] = __builtin_amdgcn_mfma_f32_16x16x32_bf16(a[fm], bfr[fn], acc[fm][fn], 0, 0, 0);
    }

    if constexpr (ACT == 2) {
        float part[2][4];
#pragma unroll
        for (int fm = 0; fm < 2; ++fm)
#pragma unroll
            for (int r = 0; r < 4; ++r) part[fm][r] = 0.f;
#pragma unroll
        for (int fm = 0; fm < 2; ++fm) {
#pragma unroll
            for (int fn = 0; fn < FN; ++fn) {
                int col = colbase + fn * 16 + lr;
                float bv = bias[col];
                float wv = Wc2[col];
#pragma unroll
                for (int r = 0; r < 4; ++r) {
                    float v = acc[fm][fn][r] + bv;
                    v = fmaxf(v, 0.f);
                    part[fm][r] += v * wv;
                }
            }
        }
#pragma unroll
        for (int fm = 0; fm < 2; ++fm)
#pragma unroll
            for (int r = 0; r < 4; ++r)
#pragma unroll
                for (int m = 1; m < 16; m <<= 1)
                    part[fm][r] += __shfl_xor(part[fm][r], m, 64);
        __shared__ float red[2][64];
        if (lr == 0) {
#pragma unroll
            for (int fm = 0; fm < 2; ++fm)
#pragma unroll
                for (int r = 0; r < 4; ++r)
                    red[wn][wm * 32 + fm * 16 + lk * 4 + r] = part[fm][r];
        }
        __syncthreads();
        if (tid < 64) Out[blockIdx.x * 64 + tid] = red[0][tid] + red[1][tid] + bc2[0];
    } else {
#pragma unroll
        for (int fm = 0; fm < 2; ++fm) {
#pragma unroll
            for (int fn = 0; fn < FN; ++fn) {
                int col = colbase + fn * 16 + lr;
                float bv = bias[col];
#pragma unroll
                for (int r = 0; r < 4; ++r) {
                    float v = acc[fm][fn][r] + bv;
                    if constexpr (ACT == 1) v = selu_f(v);
                    int row = rowbase + fm * 16 + lk * 4 + r;
                    C[(size_t)row * ldc + ccol + col] = __float2bfloat16(v);
                }
            }
        }
    }
}

extern "C" void kernel_launch(void* const* d_in, const int* in_sizes, int n_in,
                              void* d_out, int out_size, void* d_ws, size_t ws_size,
                              hipStream_t stream) {
    const float* x   = (const float*)d_in[0];
    const float* W1  = (const float*)d_in[1];
    const float* b1  = (const float*)d_in[2];
    const float* W2  = (const float*)d_in[3];
    const float* b2  = (const float*)d_in[4];
    const float* W3  = (const float*)d_in[5];
    const float* b3  = (const float*)d_in[6];
    const float* Wc1 = (const float*)d_in[7];
    const float* bc1 = (const float*)d_in[8];
    const float* Wc2 = (const float*)d_in[9];
    const float* bc2 = (const float*)d_in[10];
    float* out = (float*)d_out;

    char* ws = (char*)d_ws;
    bf16* W1T  = (bf16*)ws; ws += (size_t)2048 * 256 * 2;
    bf16* W2T  = (bf16*)ws; ws += (size_t)256 * 256 * 2;
    bf16* W3T  = (bf16*)ws; ws += (size_t)128 * 256 * 2;
    bf16* Wc1T = (bf16*)ws; ws += (size_t)256 * 2176 * 2;
    bf16* h1   = (bf16*)ws; ws += (size_t)BATCH * H_DIM * 2;
    bf16* h2   = (bf16*)ws; ws += (size_t)BATCH * H_DIM * 2;
    bf16* cin  = (bf16*)ws; ws += (size_t)BATCH * CIN_DIM * 2;

    transpose_cvt<<<2048, 256, 0, stream>>>(W1, W1T, 2048, 256, 8);
    transpose_cvt<<<256,  256, 0, stream>>>(W2, W2T, 256, 256, 8);
    transpose_cvt<<<128,  256, 0, stream>>>(W3, W3T, 256, 128, 7);
    transpose_cvt<<<2176, 256, 0, stream>>>(Wc1, Wc1T, 2176, 256, 8);

    gram_first<<<4096, 256, 0, stream>>>(x, cin);

    // h1 = selu(x @ W1 + b1)
    gemm_k<2048, 8, true, 1><<<256, 256, 0, stream>>>(x, 2048, W1T, b1, h1, 256, 0,
                                                      nullptr, nullptr, nullptr);
    // h2 = selu(h1 @ W2 + b2)
    gemm_k<256, 8, false, 1><<<256, 256, 0, stream>>>(h1, 256, W2T, b2, h2, 256, 0,
                                                      nullptr, nullptr, nullptr);
    // hoi = h2 @ W3 + b3  -> cin[:, 0:128]
    gemm_k<256, 4, false, 0><<<256, 256, 0, stream>>>(h2, 256, W3T, b3, cin, CIN_DIM, 0,
                                                      nullptr, nullptr, nullptr);
    // out = relu(cin @ Wc1 + bc1) @ Wc2 + bc2
    gemm_k<2176, 8, false, 2><<<256, 256, 0, stream>>>(cin, CIN_DIM, Wc1T, bc1, nullptr, 0, 0,
                                                       Wc2, bc2, out);
}

// Round 2
// 152.945 us; speedup vs baseline: 1.5622x; 1.5622x over previous
//
#include <hip/hip_runtime.h>
#include <hip/hip_bf16.h>

#define BATCH 16384
#define F_DIM 64
#define D_DIM 32
#define H_DIM 256
#define HO_DIM 128
#define NPAIR 2016
#define CIN_DIM 2176

typedef __hip_bfloat16 bf16;
using bf16x8 = __attribute__((ext_vector_type(8))) __bf16;
using f32x4  = __attribute__((ext_vector_type(4))) float;

__device__ inline float selu_f(float v) {
    const float scale = 1.0507009873554805f;
    const float alpha = 1.6732632423543772f;
    return v > 0.f ? scale * v : scale * alpha * (__expf(v) - 1.f);
}

__device__ inline void gload16(const void* g, void* l) {
    __builtin_amdgcn_global_load_lds(
        (const __attribute__((address_space(1))) void*)g,
        (__attribute__((address_space(3))) void*)l,
        16, 0, 0);
}

// out[n*K + k] = bf16(in[k*N + n]);  N must be a power of two (logN = log2(N))
__global__ void transpose_cvt(const float* __restrict__ in, bf16* __restrict__ out,
                              int K, int N, int logN) {
    int i = blockIdx.x * 256 + threadIdx.x;
    if (i >= K * N) return;
    int n = i & (N - 1), k = i >> logN;
    out[(size_t)n * K + k] = __float2bfloat16(in[i]);
}

// One wave per batch: gram = X * X^T (64x64, K=32) via 10 MFMAs (upper tiles),
// writes soi (2016 bf16) into cin[:,128:2144] and first_order into cin[:,2144:2176].
__global__ __launch_bounds__(256) void gram_first(const float* __restrict__ x,
                                                  bf16* __restrict__ cin) {
    __shared__ __align__(16) bf16 stage[4][NPAIR];
    int w = threadIdx.x >> 6, l = threadIdx.x & 63;
    int b = blockIdx.x * 4 + w;
    const float* X = x + (size_t)b * (F_DIM * D_DIM);
    int lr = l & 15, lk = l >> 4;

    bf16x8 xa[4];
    float fsum[8];
#pragma unroll
    for (int j = 0; j < 8; ++j) fsum[j] = 0.f;

#pragma unroll
    for (int ti = 0; ti < 4; ++ti) {
        const float* p = X + (ti * 16 + lr) * D_DIM + lk * 8;
        float4 f0 = *(const float4*)p;
        float4 f1 = *(const float4*)(p + 4);
        bf16x8 t;
        t[0] = (__bf16)f0.x; t[1] = (__bf16)f0.y; t[2] = (__bf16)f0.z; t[3] = (__bf16)f0.w;
        t[4] = (__bf16)f1.x; t[5] = (__bf16)f1.y; t[6] = (__bf16)f1.z; t[7] = (__bf16)f1.w;
        xa[ti] = t;
        fsum[0] += f0.x; fsum[1] += f0.y; fsum[2] += f0.z; fsum[3] += f0.w;
        fsum[4] += f1.x; fsum[5] += f1.y; fsum[6] += f1.z; fsum[7] += f1.w;
    }

    const int pi[10] = {0,0,0,0,1,1,1,2,2,3};
    const int pj[10] = {0,1,2,3,1,2,3,2,3,3};
    f32x4 zero = {0.f, 0.f, 0.f, 0.f};
#pragma unroll
    for (int p = 0; p < 10; ++p) {
        f32x4 g = __builtin_amdgcn_mfma_f32_16x16x32_bf16(xa[pi[p]], xa[pj[p]], zero, 0, 0, 0);
        int ib = pi[p] * 16 + lk * 4;
        int j  = pj[p] * 16 + lr;
#pragma unroll
        for (int r = 0; r < 4; ++r) {
            int i = ib + r;
            if (j > i) {
                int idx = (i * (127 - i)) / 2 + (j - i - 1);
                stage[w][idx] = __float2bfloat16(g[r]);
            }
        }
    }

#pragma unroll
    for (int m = 1; m < 16; m <<= 1)
#pragma unroll
        for (int j = 0; j < 8; ++j)
            fsum[j] += __shfl_xor(fsum[j], m, 64);
    if (lr == 0) {
        bf16* dst = cin + (size_t)b * CIN_DIM + (HO_DIM + NPAIR) + lk * 8;
#pragma unroll
        for (int j = 0; j < 8; ++j) dst[j] = __float2bfloat16(fsum[j]);
    }

    __syncthreads();
    const uint4* s4 = (const uint4*)&stage[0][0];
    int base_b = blockIdx.x * 4;
    for (int c = threadIdx.x; c < 4 * 252; c += 256) {
        int bb = c / 252, off = c - bb * 252;
        uint4 v = s4[c];
        *(uint4*)(cin + (size_t)(base_b + bb) * CIN_DIM + HO_DIM + off * 8) = v;
    }
}

// LDS-staged double-buffered GEMM. Block: 64 rows x N cols, 512 threads (8 waves, 2x4).
// Wave tile 32 x (N/4). BK=64. A row-major [M][K] (bf16, or fp32 reg-staged when AFP32).
// BT: [N][K] bf16. XOR swizzle (slot ^ row&7) pre-applied on global source, applied on reads.
// ACT: 0 = +bias, 1 = +bias,selu, 2 = +bias,relu then fused dot with Wc2 -> Out.
template<int K, int N, int ACT, bool AFP32>
__global__ __launch_bounds__(512) void gemm_lds(
    const void* __restrict__ Av,
    const bf16* __restrict__ BT,
    const float* __restrict__ bias,
    bf16* __restrict__ C, int ldc, int ccol,
    const float* __restrict__ Wc2, const float* __restrict__ bc2,
    float* __restrict__ Out)
{
    constexpr int BK = 64;
    constexpr int NT = K / BK;
    constexpr int FN = N / 64;          // N-fragments per wave
    constexpr int BST = (N * 8) / 512;  // B stage loads per thread

    __shared__ __align__(16) bf16 Abuf[2][64 * BK];
    __shared__ __align__(16) bf16 Bbuf[2][N * BK];
    __shared__ float red[4][64];

    const int tid = threadIdx.x;
    const int w = tid >> 6, l = tid & 63;
    const int wm = w >> 2, wn = w & 3;
    const int lr = l & 15, lk = l >> 4;
    const int rowblk = blockIdx.x * 64;

    const int srow = tid >> 3, sks = tid & 7;

    const bf16*  gAb = (const bf16*)Av  + (size_t)(rowblk + srow) * K + ((sks ^ (srow & 7)) * 8);
    const float* gAf = (const float*)Av + (size_t)(rowblk + srow) * K + ((sks ^ (srow & 7)) * 8);

    const bf16* gBs[BST];
#pragma unroll
    for (int s = 0; s < BST; ++s) {
        int col = s * 64 + srow;
        gBs[s] = BT + (size_t)col * K + ((sks ^ (col & 7)) * 8);
    }

    int aoff[2][2], boff[FN][2];
#pragma unroll
    for (int fm = 0; fm < 2; ++fm) {
        int arow = wm * 32 + fm * 16 + lr;
#pragma unroll
        for (int kk = 0; kk < 2; ++kk)
            aoff[fm][kk] = arow * BK + (((kk * 4 + lk) ^ (arow & 7)) * 8);
    }
#pragma unroll
    for (int fn = 0; fn < FN; ++fn) {
        int bcol = wn * (FN * 16) + fn * 16 + lr;
#pragma unroll
        for (int kk = 0; kk < 2; ++kk)
            boff[fn][kk] = bcol * BK + (((kk * 4 + lk) ^ (bcol & 7)) * 8);
    }

    f32x4 acc[2][FN];
#pragma unroll
    for (int fm = 0; fm < 2; ++fm)
#pragma unroll
        for (int fn = 0; fn < FN; ++fn)
            acc[fm][fn] = (f32x4){0.f, 0.f, 0.f, 0.f};

    float4 pA0, pA1;
    auto stage = [&](int buf, int t) {
        if constexpr (AFP32) {
            const float* p = gAf + (size_t)t * BK;
            pA0 = *(const float4*)p;
            pA1 = *(const float4*)(p + 4);
        } else {
            gload16(gAb + (size_t)t * BK, &Abuf[buf][tid * 8]);
        }
#pragma unroll
        for (int s = 0; s < BST; ++s)
            gload16(gBs[s] + (size_t)t * BK, &Bbuf[buf][(s * 512 + tid) * 8]);
    };
    auto commitA = [&](int buf) {
        if constexpr (AFP32) {
            bf16x8 v;
            v[0] = (__bf16)pA0.x; v[1] = (__bf16)pA0.y; v[2] = (__bf16)pA0.z; v[3] = (__bf16)pA0.w;
            v[4] = (__bf16)pA1.x; v[5] = (__bf16)pA1.y; v[6] = (__bf16)pA1.z; v[7] = (__bf16)pA1.w;
            *(bf16x8*)&Abuf[buf][tid * 8] = v;
        }
    };

    stage(0, 0);
    commitA(0);
    __syncthreads();

    int cur = 0;
    for (int t = 0; t < NT; ++t) {
        if (t + 1 < NT) stage(cur ^ 1, t + 1);

        bf16x8 a[2][2], bfr[FN][2];
#pragma unroll
        for (int fm = 0; fm < 2; ++fm)
#pragma unroll
            for (int kk = 0; kk < 2; ++kk)
                a[fm][kk] = *(const bf16x8*)&Abuf[cur][aoff[fm][kk]];
#pragma unroll
        for (int fn = 0; fn < FN; ++fn)
#pragma unroll
            for (int kk = 0; kk < 2; ++kk)
                bfr[fn][kk] = *(const bf16x8*)&Bbuf[cur][boff[fn][kk]];

#pragma unroll
        for (int kk = 0; kk < 2; ++kk)
#pragma unroll
            for (int fm = 0; fm < 2; ++fm)
#pragma unroll
                for (int fn = 0; fn < FN; ++fn)
                    acc[fm][fn] = __builtin_amdgcn_mfma_f32_16x16x32_bf16(
                        a[fm][kk], bfr[fn][kk], acc[fm][fn], 0, 0, 0);

        if (t + 1 < NT) commitA(cur ^ 1);
        __syncthreads();
        cur ^= 1;
    }

    if constexpr (ACT == 2) {
        float part[2][4];
#pragma unroll
        for (int fm = 0; fm < 2; ++fm)
#pragma unroll
            for (int r = 0; r < 4; ++r) part[fm][r] = 0.f;
#pragma unroll
        for (int fm = 0; fm < 2; ++fm) {
#pragma unroll
            for (int fn = 0; fn < FN; ++fn) {
                int col = wn * (FN * 16) + fn * 16 + lr;
                float bv = bias[col];
                float wv = Wc2[col];
#pragma unroll
                for (int r = 0; r < 4; ++r) {
                    float v = acc[fm][fn][r] + bv;
                    v = fmaxf(v, 0.f);
                    part[fm][r] += v * wv;
                }
            }
        }
#pragma unroll
        for (int fm = 0; fm < 2; ++fm)
#pragma unroll
            for (int r = 0; r < 4; ++r)
#pragma unroll
                for (int m = 1; m < 16; m <<= 1)
                    part[fm][r] += __shfl_xor(part[fm][r], m, 64);
        if (lr == 0) {
#pragma unroll
            for (int fm = 0; fm < 2; ++fm)
#pragma unroll
                for (int r = 0; r < 4; ++r)
                    red[wn][wm * 32 + fm * 16 + lk * 4 + r] = part[fm][r];
        }
        __syncthreads();
        if (tid < 64)
            Out[rowblk + tid] = red[0][tid] + red[1][tid] + red[2][tid] + red[3][tid] + bc2[0];
    } else {
#pragma unroll
        for (int fm = 0; fm < 2; ++fm) {
#pragma unroll
            for (int fn = 0; fn < FN; ++fn) {
                int col = wn * (FN * 16) + fn * 16 + lr;
                float bv = bias[col];
#pragma unroll
                for (int r = 0; r < 4; ++r) {
                    float v = acc[fm][fn][r] + bv;
                    if constexpr (ACT == 1) v = selu_f(v);
                    int row = rowblk + wm * 32 + fm * 16 + lk * 4 + r;
                    C[(size_t)row * ldc + ccol + col] = __float2bfloat16(v);
                }
            }
        }
    }
}

extern "C" void kernel_launch(void* const* d_in, const int* in_sizes, int n_in,
                              void* d_out, int out_size, void* d_ws, size_t ws_size,
                              hipStream_t stream) {
    const float* x   = (const float*)d_in[0];
    const float* W1  = (const float*)d_in[1];
    const float* b1  = (const float*)d_in[2];
    const float* W2  = (const float*)d_in[3];
    const float* b2  = (const float*)d_in[4];
    const float* W3  = (const float*)d_in[5];
    const float* b3  = (const float*)d_in[6];
    const float* Wc1 = (const float*)d_in[7];
    const float* bc1 = (const float*)d_in[8];
    const float* Wc2 = (const float*)d_in[9];
    const float* bc2 = (const float*)d_in[10];
    float* out = (float*)d_out;

    char* ws = (char*)d_ws;
    bf16* W1T  = (bf16*)ws; ws += (size_t)2048 * 256 * 2;
    bf16* W2T  = (bf16*)ws; ws += (size_t)256 * 256 * 2;
    bf16* W3T  = (bf16*)ws; ws += (size_t)128 * 256 * 2;
    bf16* Wc1T = (bf16*)ws; ws += (size_t)256 * 2176 * 2;
    bf16* h1   = (bf16*)ws; ws += (size_t)BATCH * H_DIM * 2;
    bf16* h2   = (bf16*)ws; ws += (size_t)BATCH * H_DIM * 2;
    bf16* cin  = (bf16*)ws; ws += (size_t)BATCH * CIN_DIM * 2;

    transpose_cvt<<<2048, 256, 0, stream>>>(W1, W1T, 2048, 256, 8);
    transpose_cvt<<<256,  256, 0, stream>>>(W2, W2T, 256, 256, 8);
    transpose_cvt<<<128,  256, 0, stream>>>(W3, W3T, 256, 128, 7);
    transpose_cvt<<<2176, 256, 0, stream>>>(Wc1, Wc1T, 2176, 256, 8);

    gram_first<<<4096, 256, 0, stream>>>(x, cin);

    // h1 = selu(x @ W1 + b1)
    gemm_lds<2048, 256, 1, true><<<256, 512, 0, stream>>>(x, W1T, b1, h1, 256, 0,
                                                          nullptr, nullptr, nullptr);
    // h2 = selu(h1 @ W2 + b2)
    gemm_lds<256, 256, 1, false><<<256, 512, 0, stream>>>(h1, W2T, b2, h2, 256, 0,
                                                          nullptr, nullptr, nullptr);
    // hoi = h2 @ W3 + b3  -> cin[:, 0:128]
    gemm_lds<256, 128, 0, false><<<256, 512, 0, stream>>>(h2, W3T, b3, cin, CIN_DIM, 0,
                                                          nullptr, nullptr, nullptr);
    // out = relu(cin @ Wc1 + bc1) @ Wc2 + bc2
    gemm_lds<2176, 256, 2, false><<<256, 512, 0, stream>>>(cin, Wc1T, bc1, nullptr, 0, 0,
                                                           Wc2, bc2, out);
}

// Round 3
// 123.301 us; speedup vs baseline: 1.9378x; 1.2404x over previous
//
#include <hip/hip_runtime.h>
#include <hip/hip_bf16.h>

#define BATCH 16384
#define F_DIM 64
#define D_DIM 32
#define H_DIM 256
#define HO_DIM 128
#define NPAIR 2016
#define CIN_DIM 2176

typedef __hip_bfloat16 bf16;
using bf16x8 = __attribute__((ext_vector_type(8))) __bf16;
using f32x4  = __attribute__((ext_vector_type(4))) float;

__device__ inline float selu_f(float v) {
    const float scale = 1.0507009873554805f;
    const float alpha = 1.6732632423543772f;
    return v > 0.f ? scale * v : scale * alpha * (__expf(v) - 1.f);
}

__device__ inline void gload16(const void* g, void* l) {
    __builtin_amdgcn_global_load_lds(
        (const __attribute__((address_space(1))) void*)g,
        (__attribute__((address_space(3))) void*)l,
        16, 0, 0);
}

// Merged weight prep: W1T [256][2048], W2T [256][256], Wc1T [256][2176] (plain
// transposed bf16), W3Tsw [128][256] transposed bf16 with LDS-image XOR swizzle
// (slot ^ (n&7)) pre-applied so a linear global_load_lds copy yields the
// swizzled LDS layout directly.
__global__ void prep(const float* __restrict__ W1, const float* __restrict__ W2,
                     const float* __restrict__ W3, const float* __restrict__ Wc1,
                     bf16* __restrict__ W1T, bf16* __restrict__ W2T,
                     bf16* __restrict__ W3Tsw, bf16* __restrict__ Wc1T) {
    int bid = blockIdx.x, tid = threadIdx.x;
    if (bid < 2048) {
        int i = bid * 256 + tid;
        int n = i & 255, k = i >> 8;
        W1T[(size_t)n * 2048 + k] = __float2bfloat16(W1[i]);
    } else if (bid < 2304) {
        int i = (bid - 2048) * 256 + tid;
        int n = i & 255, k = i >> 8;
        W2T[n * 256 + k] = __float2bfloat16(W2[i]);
    } else if (bid < 2432) {
        int i = (bid - 2304) * 256 + tid;   // i over 256*128, k-major
        int k = i >> 7, n = i & 127;
        W3Tsw[n * 256 + (((k >> 3) ^ (n & 7)) * 8) + (k & 7)] = __float2bfloat16(W3[i]);
    } else {
        int i = (bid - 2432) * 256 + tid;
        int n = i & 255, k = i >> 8;
        Wc1T[(size_t)n * 2176 + k] = __float2bfloat16(Wc1[i]);
    }
}

// Fused gram + first_order + MLP1. 256 blocks x 512 threads (8 waves), 64
// batches/block, 8 batches/wave. X read ONCE from global (fp32), kept as bf16
// MFMA fragments in registers; gram (10 MFMAs/batch) + soi + first_order
// written to cin; then MLP1 K-loop (K=2048, BK=64) with A fed from the X
// registers via swizzled ds_write, B = W1T via global_load_lds double-buffer.
__global__ __launch_bounds__(512, 2) void gram_mlp1(
    const float* __restrict__ x, const bf16* __restrict__ W1T,
    const float* __restrict__ b1, bf16* __restrict__ cin, bf16* __restrict__ h1) {
    constexpr int K = 2048;
    __shared__ __align__(16) char smraw[81920];
    bf16* Abuf0 = (bf16*)smraw;
    bf16* Abuf1 = (bf16*)(smraw + 8192);
    bf16* Bbuf0 = (bf16*)(smraw + 16384);
    bf16* Bbuf1 = (bf16*)(smraw + 49152);

    const int tid = threadIdx.x;
    const int w = tid >> 6, l = tid & 63;
    const int lr = l & 15, lk = l >> 4;
    const int wm = w >> 2, wn = w & 3;
    const int blk = blockIdx.x;
    const int batch0 = blk * 64 + w * 8;

    // ---------------- gram phase ----------------
    bf16x8 xa[8][4];
    bf16* mysoi = (bf16*)(smraw + w * 4096);
    const int pi[10] = {0,0,0,0,1,1,1,2,2,3};
    const int pj[10] = {0,1,2,3,1,2,3,2,3,3};

    float4 pf[2][8];
#pragma unroll
    for (int ti = 0; ti < 4; ++ti) {
        const float* p = x + (size_t)batch0 * 2048 + (ti * 16 + lr) * 32 + lk * 8;
        pf[0][ti * 2]     = *(const float4*)p;
        pf[0][ti * 2 + 1] = *(const float4*)(p + 4);
    }

#pragma unroll
    for (int bb = 0; bb < 8; ++bb) {
        if (bb < 7) {
#pragma unroll
            for (int ti = 0; ti < 4; ++ti) {
                const float* p = x + (size_t)(batch0 + bb + 1) * 2048 + (ti * 16 + lr) * 32 + lk * 8;
                pf[(bb + 1) & 1][ti * 2]     = *(const float4*)p;
                pf[(bb + 1) & 1][ti * 2 + 1] = *(const float4*)(p + 4);
            }
        }
        // convert current batch to bf16 frags + fsum
        float fsum[8];
#pragma unroll
        for (int j = 0; j < 8; ++j) fsum[j] = 0.f;
#pragma unroll
        for (int ti = 0; ti < 4; ++ti) {
            float4 f0 = pf[bb & 1][ti * 2];
            float4 f1 = pf[bb & 1][ti * 2 + 1];
            bf16x8 t;
            t[0] = (__bf16)f0.x; t[1] = (__bf16)f0.y; t[2] = (__bf16)f0.z; t[3] = (__bf16)f0.w;
            t[4] = (__bf16)f1.x; t[5] = (__bf16)f1.y; t[6] = (__bf16)f1.z; t[7] = (__bf16)f1.w;
            xa[bb][ti] = t;
            fsum[0] += f0.x; fsum[1] += f0.y; fsum[2] += f0.z; fsum[3] += f0.w;
            fsum[4] += f1.x; fsum[5] += f1.y; fsum[6] += f1.z; fsum[7] += f1.w;
        }
#pragma unroll
        for (int m = 1; m < 16; m <<= 1)
#pragma unroll
            for (int j = 0; j < 8; ++j)
                fsum[j] += __shfl_xor(fsum[j], m, 64);
        if (lr == 0) {
            bf16x8 fv;
#pragma unroll
            for (int j = 0; j < 8; ++j) fv[j] = (__bf16)fsum[j];
            *(bf16x8*)(cin + (size_t)(batch0 + bb) * CIN_DIM + (HO_DIM + NPAIR) + lk * 8) = fv;
        }
        // gram MFMAs -> soi stage (wave-local LDS slice)
        f32x4 zero = {0.f, 0.f, 0.f, 0.f};
#pragma unroll
        for (int p = 0; p < 10; ++p) {
            f32x4 g = __builtin_amdgcn_mfma_f32_16x16x32_bf16(xa[bb][pi[p]], xa[bb][pj[p]], zero, 0, 0, 0);
            int ib = pi[p] * 16 + lk * 4;
            int j  = pj[p] * 16 + lr;
#pragma unroll
            for (int r = 0; r < 4; ++r) {
                int i = ib + r;
                if (j > i) {
                    int idx = (i * (127 - i)) / 2 + (j - i - 1);
                    mysoi[idx] = __float2bfloat16(g[r]);
                }
            }
        }
        // coalesced copy out: 252 uint4
        const uint4* s4 = (const uint4*)mysoi;
        uint4* dst = (uint4*)(cin + (size_t)(batch0 + bb) * CIN_DIM + HO_DIM);
        for (int c = l; c < 252; c += 64) dst[c] = s4[c];
    }

    __syncthreads();   // LDS reuse: soi slices -> A/B dbuf

    // ---------------- MLP1 phase ----------------
    const bf16* gBs[4];
#pragma unroll
    for (int s = 0; s < 4; ++s) {
        int col = s * 64 + (tid >> 3);
        gBs[s] = W1T + (size_t)col * K + (((tid & 7) ^ (col & 7)) * 8);
    }
    int aoff[2][2], boff[4][2];
#pragma unroll
    for (int fm = 0; fm < 2; ++fm) {
        int arow = wm * 32 + fm * 16 + lr;
#pragma unroll
        for (int kk = 0; kk < 2; ++kk)
            aoff[fm][kk] = arow * 64 + (((kk * 4 + lk) ^ (arow & 7)) * 8);
    }
#pragma unroll
    for (int fn = 0; fn < 4; ++fn) {
        int bcol = wn * 64 + fn * 16 + lr;
#pragma unroll
        for (int kk = 0; kk < 2; ++kk)
            boff[fn][kk] = bcol * 64 + (((kk * 4 + lk) ^ (bcol & 7)) * 8);
    }

    f32x4 acc[2][4];
#pragma unroll
    for (int fm = 0; fm < 2; ++fm)
#pragma unroll
        for (int fn = 0; fn < 4; ++fn)
            acc[fm][fn] = (f32x4){0.f, 0.f, 0.f, 0.f};

#define WRITEA(tt, DST) { \
    const int f0_ = 2 * (tt); \
    const int lrA_ = f0_ & 15, lrB_ = (f0_ + 1) & 15; \
    int delta_ = (lr == lrA_) ? 0 : ((lr == lrB_) ? 1 : -1); \
    if (delta_ >= 0) { \
        int cs_ = delta_ * 4 + lk; \
        _Pragma("unroll") \
        for (int bb_ = 0; bb_ < 8; ++bb_) { \
            int row_ = w * 8 + bb_; \
            *(bf16x8*)((DST) + row_ * 64 + ((cs_ ^ (row_ & 7)) * 8)) = xa[bb_][(tt) >> 3]; \
        } } }

    // prologue
    WRITEA(0, Abuf0);
#pragma unroll
    for (int s = 0; s < 4; ++s)
        gload16(gBs[s], Bbuf0 + (s * 512 + tid) * 8);
    __syncthreads();

#pragma unroll
    for (int t = 0; t < 32; ++t) {
        bf16* Ac = (t & 1) ? Abuf1 : Abuf0;
        bf16* Bc = (t & 1) ? Bbuf1 : Bbuf0;
        bf16* An = (t & 1) ? Abuf0 : Abuf1;
        bf16* Bn = (t & 1) ? Bbuf0 : Bbuf1;
        if (t < 31) {
#pragma unroll
            for (int s = 0; s < 4; ++s)
                gload16(gBs[s] + (size_t)(t + 1) * 64, Bn + (s * 512 + tid) * 8);
        }
        bf16x8 a[2][2], bfr[4][2];
#pragma unroll
        for (int fm = 0; fm < 2; ++fm)
#pragma unroll
            for (int kk = 0; kk < 2; ++kk)
                a[fm][kk] = *(const bf16x8*)(Ac + aoff[fm][kk]);
#pragma unroll
        for (int fn = 0; fn < 4; ++fn)
#pragma unroll
            for (int kk = 0; kk < 2; ++kk)
                bfr[fn][kk] = *(const bf16x8*)(Bc + boff[fn][kk]);
#pragma unroll
        for (int kk = 0; kk < 2; ++kk)
#pragma unroll
            for (int fm = 0; fm < 2; ++fm)
#pragma unroll
                for (int fn = 0; fn < 4; ++fn)
                    acc[fm][fn] = __builtin_amdgcn_mfma_f32_16x16x32_bf16(
                        a[fm][kk], bfr[fn][kk], acc[fm][fn], 0, 0, 0);
        if (t < 31) WRITEA(t + 1, An);
        __syncthreads();
    }
#undef WRITEA

    // epilogue: h1 = selu(acc + b1)
#pragma unroll
    for (int fm = 0; fm < 2; ++fm) {
#pragma unroll
        for (int fn = 0; fn < 4; ++fn) {
            int col = wn * 64 + fn * 16 + lr;
            float bv = b1[col];
#pragma unroll
            for (int r = 0; r < 4; ++r) {
                float v = selu_f(acc[fm][fn][r] + bv);
                int row = blk * 64 + wm * 32 + fm * 16 + lk * 4 + r;
                h1[(size_t)row * 256 + col] = __float2bfloat16(v);
            }
        }
    }
}

// Fused MLP2+MLP3: h2 = selu(h1@W2+b2) kept in LDS, hoi = h2@W3+b3 -> cin[:,0:128]
__global__ __launch_bounds__(512, 2) void mlp23(
    const bf16* __restrict__ h1, const bf16* __restrict__ W2T, const float* __restrict__ b2,
    const bf16* __restrict__ W3Tsw, const float* __restrict__ b3, bf16* __restrict__ cin) {
    __shared__ __align__(16) char smraw[147456];   // [0,16K) A dbuf, [16K,80K) B dbuf, [80K,144K) W3; h2 overlays [0,32K)
    bf16* Abuf0 = (bf16*)smraw;
    bf16* Abuf1 = (bf16*)(smraw + 8192);
    bf16* Bbuf0 = (bf16*)(smraw + 16384);
    bf16* Bbuf1 = (bf16*)(smraw + 49152);
    bf16* w3l   = (bf16*)(smraw + 81920);
    bf16* h2sw  = (bf16*)smraw;

    const int tid = threadIdx.x;
    const int w = tid >> 6, l = tid & 63;
    const int lr = l & 15, lk = l >> 4;
    const int wm = w >> 2, wn = w & 3;
    const int rowblk = blockIdx.x * 64;
    const int srow = tid >> 3, sks = tid & 7;

    // stage all of W3 (pre-swizzled image, linear copy)
#pragma unroll
    for (int s = 0; s < 8; ++s)
        gload16(W3Tsw + (size_t)(s * 512 + tid) * 8, w3l + (s * 512 + tid) * 8);

    const bf16* gA = h1 + (size_t)(rowblk + srow) * 256 + ((sks ^ (srow & 7)) * 8);
    const bf16* gBs[4];
#pragma unroll
    for (int s = 0; s < 4; ++s) {
        int col = s * 64 + srow;
        gBs[s] = W2T + (size_t)col * 256 + ((sks ^ (col & 7)) * 8);
    }
    int aoff[2][2], boff[4][2];
#pragma unroll
    for (int fm = 0; fm < 2; ++fm) {
        int arow = wm * 32 + fm * 16 + lr;
#pragma unroll
        for (int kk = 0; kk < 2; ++kk)
            aoff[fm][kk] = arow * 64 + (((kk * 4 + lk) ^ (arow & 7)) * 8);
    }
#pragma unroll
    for (int fn = 0; fn < 4; ++fn) {
        int bcol = wn * 64 + fn * 16 + lr;
#pragma unroll
        for (int kk = 0; kk < 2; ++kk)
            boff[fn][kk] = bcol * 64 + (((kk * 4 + lk) ^ (bcol & 7)) * 8);
    }

    f32x4 acc[2][4];
#pragma unroll
    for (int fm = 0; fm < 2; ++fm)
#pragma unroll
        for (int fn = 0; fn < 4; ++fn)
            acc[fm][fn] = (f32x4){0.f, 0.f, 0.f, 0.f};

    gload16(gA, Abuf0 + tid * 8);
#pragma unroll
    for (int s = 0; s < 4; ++s)
        gload16(gBs[s], Bbuf0 + (s * 512 + tid) * 8);
    __syncthreads();

#pragma unroll
    for (int t = 0; t < 4; ++t) {
        bf16* Ac = (t & 1) ? Abuf1 : Abuf0;
        bf16* Bc = (t & 1) ? Bbuf1 : Bbuf0;
        bf16* An = (t & 1) ? Abuf0 : Abuf1;
        bf16* Bn = (t & 1) ? Bbuf0 : Bbuf1;
        if (t < 3) {
            gload16(gA + (size_t)(t + 1) * 64, An + tid * 8);
#pragma unroll
            for (int s = 0; s < 4; ++s)
                gload16(gBs[s] + (size_t)(t + 1) * 64, Bn + (s * 512 + tid) * 8);
        }
        bf16x8 a[2][2], bfr[4][2];
#pragma unroll
        for (int fm = 0; fm < 2; ++fm)
#pragma unroll
            for (int kk = 0; kk < 2; ++kk)
                a[fm][kk] = *(const bf16x8*)(Ac + aoff[fm][kk]);
#pragma unroll
        for (int fn = 0; fn < 4; ++fn)
#pragma unroll
            for (int kk = 0; kk < 2; ++kk)
                bfr[fn][kk] = *(const bf16x8*)(Bc + boff[fn][kk]);
#pragma unroll
        for (int kk = 0; kk < 2; ++kk)
#pragma unroll
            for (int fm = 0; fm < 2; ++fm)
#pragma unroll
                for (int fn = 0; fn < 4; ++fn)
                    acc[fm][fn] = __builtin_amdgcn_mfma_f32_16x16x32_bf16(
                        a[fm][kk], bfr[fn][kk], acc[fm][fn], 0, 0, 0);
        __syncthreads();
    }

    // h2 (selu) -> LDS swizzled [64][256]
#pragma unroll
    for (int fm = 0; fm < 2; ++fm) {
#pragma unroll
        for (int fn = 0; fn < 4; ++fn) {
            int col = wn * 64 + fn * 16 + lr;
            float bv = b2[col];
#pragma unroll
            for (int r = 0; r < 4; ++r) {
                float v = selu_f(acc[fm][fn][r] + bv);
                int row = wm * 32 + fm * 16 + lk * 4 + r;
                h2sw[row * 256 + (((col >> 3) ^ (row & 7)) * 8) + (col & 7)] = __float2bfloat16(v);
            }
        }
    }
    __syncthreads();

    // phase B: hoi = h2 @ W3 + b3 (N=128), wave tile 32x32
    f32x4 acc2[2][2];
#pragma unroll
    for (int fm = 0; fm < 2; ++fm)
#pragma unroll
        for (int fn = 0; fn < 2; ++fn)
            acc2[fm][fn] = (f32x4){0.f, 0.f, 0.f, 0.f};
#pragma unroll
    for (int ks = 0; ks < 8; ++ks) {
        bf16x8 a2[2], b2f[2];
#pragma unroll
        for (int fm = 0; fm < 2; ++fm) {
            int arow = wm * 32 + fm * 16 + lr;
            a2[fm] = *(const bf16x8*)(h2sw + arow * 256 + (((ks * 4 + lk) ^ (arow & 7)) * 8));
        }
#pragma unroll
        for (int fn = 0; fn < 2; ++fn) {
            int ncol = wn * 32 + fn * 16 + lr;
            b2f[fn] = *(const bf16x8*)(w3l + ncol * 256 + (((ks * 4 + lk) ^ (ncol & 7)) * 8));
        }
#pragma unroll
        for (int fm = 0; fm < 2; ++fm)
#pragma unroll
            for (int fn = 0; fn < 2; ++fn)
                acc2[fm][fn] = __builtin_amdgcn_mfma_f32_16x16x32_bf16(
                    a2[fm], b2f[fn], acc2[fm][fn], 0, 0, 0);
    }
#pragma unroll
    for (int fm = 0; fm < 2; ++fm) {
#pragma unroll
        for (int fn = 0; fn < 2; ++fn) {
            int col = wn * 32 + fn * 16 + lr;
            float bv = b3[col];
#pragma unroll
            for (int r = 0; r < 4; ++r) {
                float v = acc2[fm][fn][r] + bv;
                int row = rowblk + wm * 32 + fm * 16 + lk * 4 + r;
                cin[(size_t)row * CIN_DIM + col] = __float2bfloat16(v);
            }
        }
    }
}

// Head GEMM (ACT==2 path of the R2 template): out = relu(cin@Wc1+bc1)@Wc2+bc2
template<int K, int N>
__global__ __launch_bounds__(512) void gemm_head(
    const bf16* __restrict__ A,
    const bf16* __restrict__ BT,
    const float* __restrict__ bias,
    const float* __restrict__ Wc2, const float* __restrict__ bc2,
    float* __restrict__ Out)
{
    constexpr int BK = 64;
    constexpr int NT = K / BK;
    constexpr int FN = N / 64;
    constexpr int BST = (N * 8) / 512;

    __shared__ __align__(16) bf16 Abuf[2][64 * BK];
    __shared__ __align__(16) bf16 Bbuf[2][N * BK];
    __shared__ float red[4][64];

    const int tid = threadIdx.x;
    const int w = tid >> 6, l = tid & 63;
    const int wm = w >> 2, wn = w & 3;
    const int lr = l & 15, lk = l >> 4;
    const int rowblk = blockIdx.x * 64;
    const int srow = tid >> 3, sks = tid & 7;

    const bf16* gAb = A + (size_t)(rowblk + srow) * K + ((sks ^ (srow & 7)) * 8);
    const bf16* gBs[BST];
#pragma unroll
    for (int s = 0; s < BST; ++s) {
        int col = s * 64 + srow;
        gBs[s] = BT + (size_t)col * K + ((sks ^ (col & 7)) * 8);
    }

    int aoff[2][2], boff[FN][2];
#pragma unroll
    for (int fm = 0; fm < 2; ++fm) {
        int arow = wm * 32 + fm * 16 + lr;
#pragma unroll
        for (int kk = 0; kk < 2; ++kk)
            aoff[fm][kk] = arow * BK + (((kk * 4 + lk) ^ (arow & 7)) * 8);
    }
#pragma unroll
    for (int fn = 0; fn < FN; ++fn) {
        int bcol = wn * (FN * 16) + fn * 16 + lr;
#pragma unroll
        for (int kk = 0; kk < 2; ++kk)
            boff[fn][kk] = bcol * BK + (((kk * 4 + lk) ^ (bcol & 7)) * 8);
    }

    f32x4 acc[2][FN];
#pragma unroll
    for (int fm = 0; fm < 2; ++fm)
#pragma unroll
        for (int fn = 0; fn < FN; ++fn)
            acc[fm][fn] = (f32x4){0.f, 0.f, 0.f, 0.f};

    auto stage = [&](int buf, int t) {
        gload16(gAb + (size_t)t * BK, &Abuf[buf][tid * 8]);
#pragma unroll
        for (int s = 0; s < BST; ++s)
            gload16(gBs[s] + (size_t)t * BK, &Bbuf[buf][(s * 512 + tid) * 8]);
    };

    stage(0, 0);
    __syncthreads();

    int cur = 0;
    for (int t = 0; t < NT; ++t) {
        if (t + 1 < NT) stage(cur ^ 1, t + 1);
        bf16x8 a[2][2], bfr[FN][2];
#pragma unroll
        for (int fm = 0; fm < 2; ++fm)
#pragma unroll
            for (int kk = 0; kk < 2; ++kk)
                a[fm][kk] = *(const bf16x8*)&Abuf[cur][aoff[fm][kk]];
#pragma unroll
        for (int fn = 0; fn < FN; ++fn)
#pragma unroll
            for (int kk = 0; kk < 2; ++kk)
                bfr[fn][kk] = *(const bf16x8*)&Bbuf[cur][boff[fn][kk]];
#pragma unroll
        for (int kk = 0; kk < 2; ++kk)
#pragma unroll
            for (int fm = 0; fm < 2; ++fm)
#pragma unroll
                for (int fn = 0; fn < FN; ++fn)
                    acc[fm][fn] = __builtin_amdgcn_mfma_f32_16x16x32_bf16(
                        a[fm][kk], bfr[fn][kk], acc[fm][fn], 0, 0, 0);
        __syncthreads();
        cur ^= 1;
    }

    float part[2][4];
#pragma unroll
    for (int fm = 0; fm < 2; ++fm)
#pragma unroll
        for (int r = 0; r < 4; ++r) part[fm][r] = 0.f;
#pragma unroll
    for (int fm = 0; fm < 2; ++fm) {
#pragma unroll
        for (int fn = 0; fn < FN; ++fn) {
            int col = wn * (FN * 16) + fn * 16 + lr;
            float bv = bias[col];
            float wv = Wc2[col];
#pragma unroll
            for (int r = 0; r < 4; ++r) {
                float v = acc[fm][fn][r] + bv;
                v = fmaxf(v, 0.f);
                part[fm][r] += v * wv;
            }
        }
    }
#pragma unroll
    for (int fm = 0; fm < 2; ++fm)
#pragma unroll
        for (int r = 0; r < 4; ++r)
#pragma unroll
            for (int m = 1; m < 16; m <<= 1)
                part[fm][r] += __shfl_xor(part[fm][r], m, 64);
    if (lr == 0) {
#pragma unroll
        for (int fm = 0; fm < 2; ++fm)
#pragma unroll
            for (int r = 0; r < 4; ++r)
                red[wn][wm * 32 + fm * 16 + lk * 4 + r] = part[fm][r];
    }
    __syncthreads();
    if (tid < 64)
        Out[rowblk + tid] = red[0][tid] + red[1][tid] + red[2][tid] + red[3][tid] + bc2[0];
}

extern "C" void kernel_launch(void* const* d_in, const int* in_sizes, int n_in,
                              void* d_out, int out_size, void* d_ws, size_t ws_size,
                              hipStream_t stream) {
    const float* x   = (const float*)d_in[0];
    const float* W1  = (const float*)d_in[1];
    const float* b1  = (const float*)d_in[2];
    const float* W2  = (const float*)d_in[3];
    const float* b2  = (const float*)d_in[4];
    const float* W3  = (const float*)d_in[5];
    const float* b3  = (const float*)d_in[6];
    const float* Wc1 = (const float*)d_in[7];
    const float* bc1 = (const float*)d_in[8];
    const float* Wc2 = (const float*)d_in[9];
    const float* bc2 = (const float*)d_in[10];
    float* out = (float*)d_out;

    char* ws = (char*)d_ws;
    bf16* W1T   = (bf16*)ws; ws += (size_t)256 * 2048 * 2;
    bf16* W2T   = (bf16*)ws; ws += (size_t)256 * 256 * 2;
    bf16* W3Tsw = (bf16*)ws; ws += (size_t)128 * 256 * 2;
    bf16* Wc1T  = (bf16*)ws; ws += (size_t)256 * 2176 * 2;
    bf16* h1    = (bf16*)ws; ws += (size_t)BATCH * H_DIM * 2;
    bf16* cin   = (bf16*)ws; ws += (size_t)BATCH * CIN_DIM * 2;

    prep<<<4608, 256, 0, stream>>>(W1, W2, W3, Wc1, W1T, W2T, W3Tsw, Wc1T);
    gram_mlp1<<<256, 512, 0, stream>>>(x, W1T, b1, cin, h1);
    mlp23<<<256, 512, 0, stream>>>(h1, W2T, b2, W3Tsw, b3, cin);
    gemm_head<2176, 256><<<256, 512, 0, stream>>>(cin, Wc1T, bc1, Wc2, bc2, out);
}